// Round 7
// baseline (64.312 us; speedup 1.0000x reference)
//
#include <hip/hip_runtime.h>

// SplineDisp: field[v] = ma @ (g(v) + cubic_bspline_pull(coeff, g(v))),
// g(v) = fa @ v, fa = inv(affine)@fix_affine, ma = inv(mov_affine)@affine.
// Fixed size: coeff [80,80,80,3] f32, out [160,160,160,3] f32.
// R7: SINGLE fully-fused kernel. Block = 8x8x8 output tile; coeff slab,
// z/y intermediates all in LDS; matrices computed per-block by thread 0
// (no setup kernel, no workspace, no global intermediates, one launch).
// Separable fast path requires fa axis-aligned with diag in (0,1]
// (12-tap windows per axis cover 8 outputs); else uniform fallback to
// direct 64-tap. LDS ~40.5 KB -> 4 blocks/CU.

#define CX 80
#define FD 160
#define IT 8
#define JT 8
#define KT 8
#define NXW 12
#define NYW 12
#define NZW 12

__device__ inline void inv4(const float* m, float* inv) {
    inv[0]  =  m[5]*m[10]*m[15] - m[5]*m[11]*m[14] - m[9]*m[6]*m[15] + m[9]*m[7]*m[14] + m[13]*m[6]*m[11] - m[13]*m[7]*m[10];
    inv[4]  = -m[4]*m[10]*m[15] + m[4]*m[11]*m[14] + m[8]*m[6]*m[15] - m[8]*m[7]*m[14] - m[12]*m[6]*m[11] + m[12]*m[7]*m[10];
    inv[8]  =  m[4]*m[9]*m[15]  - m[4]*m[11]*m[13] - m[8]*m[5]*m[15] + m[8]*m[7]*m[13] + m[12]*m[5]*m[11] - m[12]*m[7]*m[9];
    inv[12] = -m[4]*m[9]*m[14]  + m[4]*m[10]*m[13] + m[8]*m[5]*m[14] - m[8]*m[6]*m[13] - m[12]*m[5]*m[10] + m[12]*m[6]*m[9];
    inv[1]  = -m[1]*m[10]*m[15] + m[1]*m[11]*m[14] + m[9]*m[2]*m[15] - m[9]*m[3]*m[14] - m[13]*m[2]*m[11] + m[13]*m[3]*m[10];
    inv[5]  =  m[0]*m[10]*m[15] - m[0]*m[11]*m[14] - m[8]*m[2]*m[15] + m[8]*m[3]*m[14] + m[12]*m[2]*m[11] - m[12]*m[3]*m[10];
    inv[9]  = -m[0]*m[9]*m[15]  + m[0]*m[11]*m[13] + m[8]*m[1]*m[15] - m[8]*m[3]*m[13] - m[12]*m[1]*m[11] + m[12]*m[3]*m[9];
    inv[13] =  m[0]*m[9]*m[14]  - m[0]*m[10]*m[13] - m[8]*m[1]*m[14] + m[8]*m[2]*m[13] + m[12]*m[1]*m[10] - m[12]*m[2]*m[9];
    inv[2]  =  m[1]*m[6]*m[15]  - m[1]*m[7]*m[14]  - m[5]*m[2]*m[15] + m[5]*m[3]*m[14] + m[13]*m[2]*m[7]  - m[13]*m[3]*m[6];
    inv[6]  = -m[0]*m[6]*m[15]  + m[0]*m[7]*m[14]  + m[4]*m[2]*m[15] - m[4]*m[3]*m[14] - m[12]*m[2]*m[7]  + m[12]*m[3]*m[6];
    inv[10] =  m[0]*m[5]*m[15]  - m[0]*m[7]*m[13]  - m[4]*m[1]*m[15] + m[4]*m[3]*m[13] + m[12]*m[1]*m[7]  - m[12]*m[3]*m[5];
    inv[14] = -m[0]*m[5]*m[14]  + m[0]*m[6]*m[13]  + m[4]*m[1]*m[14] - m[4]*m[2]*m[13] - m[12]*m[1]*m[6]  + m[12]*m[2]*m[5];
    inv[3]  = -m[1]*m[6]*m[11]  + m[1]*m[7]*m[10]  + m[5]*m[2]*m[11] - m[5]*m[3]*m[10] - m[9]*m[2]*m[7]   + m[9]*m[3]*m[6];
    inv[7]  =  m[0]*m[6]*m[11]  - m[0]*m[7]*m[10]  - m[4]*m[2]*m[11] + m[4]*m[3]*m[10] + m[8]*m[2]*m[7]   - m[8]*m[3]*m[6];
    inv[11] = -m[0]*m[5]*m[11]  + m[0]*m[7]*m[9]   + m[4]*m[1]*m[11] - m[4]*m[3]*m[9]  - m[8]*m[1]*m[7]   + m[8]*m[3]*m[5];
    inv[15] =  m[0]*m[5]*m[10]  - m[0]*m[6]*m[9]   - m[4]*m[1]*m[10] + m[4]*m[2]*m[9]  + m[8]*m[1]*m[6]   - m[8]*m[2]*m[5];
    float det = m[0]*inv[0] + m[1]*inv[4] + m[2]*inv[8] + m[3]*inv[12];
    float rdet = 1.0f / det;
    for (int i = 0; i < 16; ++i) inv[i] *= rdet;
}

__device__ inline float4 bspw(float t) {
    float t2 = t * t;
    float t3 = t2 * t;
    const float s = 1.0f / 6.0f;
    float4 w;
    w.x = (1.f - 3.f*t + 3.f*t2 - t3) * s;
    w.y = (4.f - 6.f*t2 + 3.f*t3) * s;
    w.z = (1.f + 3.f*t + 3.f*t2 - 3.f*t3) * s;
    w.w = t3 * s;
    return w;
}

__device__ inline int wrap80(int v) {
    int r = v % CX;
    return (r < 0) ? r + CX : r;
}

__global__ __launch_bounds__(256, 4) void spline_fused(const float* __restrict__ coeff,
                                                       const float* __restrict__ affine,
                                                       const float* __restrict__ fix_aff,
                                                       const float* __restrict__ mov_aff,
                                                       float* __restrict__ out) {
    __shared__ float sM[34];                          // fa[0..15], ma[16..31], flag[32]
    __shared__ __align__(16) float reg2[NXW*NYW*NZW*3]; // slab (20736 B), later t2
    __shared__ float4 t1[NXW*NYW*KT];                 // 18432 B
    __shared__ float4 zw[KT], yw[JT], xw[IT];
    __shared__ int zb[KT], yb[JT], xb[IT];
    __shared__ int rowbase[NXW*NYW];
    __shared__ int zoffs[NZW*3];

    const int tid = threadIdx.x;

    if (tid == 0) {
        float invA[16], invM[16];
        inv4(affine, invA);
        inv4(mov_aff, invM);
        for (int r = 0; r < 4; ++r)
            for (int c = 0; c < 4; ++c) {
                float s1 = 0.f, s2 = 0.f;
                for (int k = 0; k < 4; ++k) {
                    s1 += invA[r*4+k] * fix_aff[k*4+c];
                    s2 += invM[r*4+k] * affine[k*4+c];
                }
                sM[r*4+c] = s1;
                sM[16 + r*4+c] = s2;
            }
        float od = fabsf(sM[1]) + fabsf(sM[2]) + fabsf(sM[4]) +
                   fabsf(sM[6]) + fabsf(sM[8]) + fabsf(sM[9]);
        int ok = (od < 1e-20f)
              && (sM[0]  > 0.f) && (sM[0]  <= 1.f)
              && (sM[5]  > 0.f) && (sM[5]  <= 1.f)
              && (sM[10] > 0.f) && (sM[10] <= 1.f);
        sM[32] = ok ? 1.f : 0.f;
    }
    __syncthreads();

    const int bid = blockIdx.x;
    const int kt = bid % 20;
    const int jt = (bid / 20) % 20;
    const int it = bid / 400;
    const int i0 = it * IT, j0 = jt * JT, k0 = kt * KT;

    if (sM[32] != 0.f) {
        const float sx = sM[0], ox = sM[3];
        const float sy = sM[5], oy = sM[7];
        const float sz = sM[10], oz = sM[11];
        const int bx0 = (int)floorf(sx * (float)i0 + ox) - 1;
        const int by0 = (int)floorf(sy * (float)j0 + oy) - 1;
        const int bz0 = (int)floorf(sz * (float)k0 + oz) - 1;

        if (tid < KT) {
            float g = sz * (float)(k0 + tid) + oz;
            float fg = floorf(g);
            zw[tid] = bspw(g - fg);
            zb[tid] = ((int)fg - 1) - bz0;          // in [0, NZW-4]
        } else if (tid < KT + JT) {
            int j = tid - KT;
            float g = sy * (float)(j0 + j) + oy;
            float fg = floorf(g);
            yw[j] = bspw(g - fg);
            yb[j] = ((int)fg - 1) - by0;
        } else if (tid < KT + JT + IT) {
            int i = tid - KT - JT;
            float g = sx * (float)(i0 + i) + ox;
            float fg = floorf(g);
            xw[i] = bspw(g - fg);
            xb[i] = ((int)fg - 1) - bx0;
        }
        if (tid < NXW * NYW) {
            int x = tid / NYW;
            int y = tid - x * NYW;
            rowbase[tid] = (wrap80(bx0 + x) * CX + wrap80(by0 + y)) * CX * 3;
        }
        if (tid < NZW * 3) {
            int z = tid / 3;
            zoffs[tid] = wrap80(bz0 + z) * 3 + (tid - z * 3);
        }
        __syncthreads();

        // stage coeff slab [row=(x,y)][z][c], 5184 floats
        for (int e = tid; e < NXW*NYW*NZW*3; e += 256) {
            int row = e / (NZW*3);
            int zc  = e - row * (NZW*3);
            reg2[e] = coeff[rowbase[row] + zoffs[zc]];
        }
        __syncthreads();

        // z-interp: t1[xy][k], 1152 items
        for (int q = tid; q < NXW*NYW*KT; q += 256) {
            int k  = q & (KT-1);
            int xy = q >> 3;
            const float* s = reg2 + xy * (NZW*3) + zb[k] * 3;
            float4 w = zw[k];
            float4 v;
            v.x = w.x*s[0] + w.y*s[3] + w.z*s[6] + w.w*s[9];
            v.y = w.x*s[1] + w.y*s[4] + w.z*s[7] + w.w*s[10];
            v.z = w.x*s[2] + w.y*s[5] + w.z*s[8] + w.w*s[11];
            v.w = 0.f;
            t1[q] = v;
        }
        __syncthreads();

        // y-interp: t2[x][j][k] aliased over reg2, 768 items
        float4* t2 = (float4*)reg2;
        for (int q = tid; q < NXW*JT*KT; q += 256) {
            int k = q & (KT-1);
            int rest = q >> 3;          // x*JT + j
            int j = rest & (JT-1);
            int x = rest >> 3;
            const float4* p = t1 + (x * NYW + yb[j]) * KT + k;
            float4 w = yw[j];
            float4 A = p[0], B = p[KT], C = p[2*KT], D = p[3*KT];
            float4 v;
            v.x = w.x*A.x + w.y*B.x + w.z*C.x + w.w*D.x;
            v.y = w.x*A.y + w.y*B.y + w.z*C.y + w.w*D.y;
            v.z = w.x*A.z + w.y*B.z + w.z*C.z + w.w*D.z;
            v.w = 0.f;
            t2[q] = v;
        }
        __syncthreads();

        // x-interp + displacement + ma affine, 512 outputs
        const float ma0 = sM[16], ma1 = sM[17], ma2  = sM[18], ma3  = sM[19];
        const float ma4 = sM[20], ma5 = sM[21], ma6  = sM[22], ma7  = sM[23];
        const float ma8 = sM[24], ma9 = sM[25], ma10 = sM[26], ma11 = sM[27];
        for (int q = tid; q < IT*JT*KT; q += 256) {
            int k = q & (KT-1);
            int rest = q >> 3;
            int j = rest & (JT-1);
            int i = rest >> 3;
            const float4* p = t2 + (xb[i] * JT + j) * KT + k;
            float4 w = xw[i];
            float4 A = p[0], B = p[JT*KT], C = p[2*JT*KT], D = p[3*JT*KT];
            float a0 = w.x*A.x + w.y*B.x + w.z*C.x + w.w*D.x;
            float a1 = w.x*A.y + w.y*B.y + w.z*C.y + w.w*D.y;
            float a2 = w.x*A.z + w.y*B.z + w.z*C.z + w.w*D.z;
            float gx = sx * (float)(i0 + i) + ox;
            float gy = sy * (float)(j0 + j) + oy;
            float gz = sz * (float)(k0 + k) + oz;
            float ux = gx + a0, uy = gy + a1, uz = gz + a2;
            size_t o = (((size_t)(i0 + i) * FD + (j0 + j)) * FD + (k0 + k)) * 3;
            out[o + 0] = ma0*ux + ma1*uy + ma2 *uz + ma3;
            out[o + 1] = ma4*ux + ma5*uy + ma6 *uz + ma7;
            out[o + 2] = ma8*ux + ma9*uy + ma10*uz + ma11;
        }
    } else {
        // non-separable fallback: direct 64-tap per output (uniform branch)
        for (int q = tid; q < IT*JT*KT; q += 256) {
            int k = k0 + (q & (KT-1));
            int rest = q >> 3;
            int j = j0 + (rest & (JT-1));
            int i = i0 + (rest >> 3);
            float fi = (float)i, fj = (float)j, fk = (float)k;
            float gx = sM[0]*fi + sM[1]*fj + sM[2]*fk  + sM[3];
            float gy = sM[4]*fi + sM[5]*fj + sM[6]*fk  + sM[7];
            float gz = sM[8]*fi + sM[9]*fj + sM[10]*fk + sM[11];
            float fx = floorf(gx), fy = floorf(gy), fz = floorf(gz);
            float4 wx = bspw(gx - fx), wy = bspw(gy - fy), wz = bspw(gz - fz);
            float wxa[4] = {wx.x, wx.y, wx.z, wx.w};
            float wya[4] = {wy.x, wy.y, wy.z, wy.w};
            float wza[4] = {wz.x, wz.y, wz.z, wz.w};
            int bxw = wrap80((int)fx - 1);
            int byw = wrap80((int)fy - 1);
            int bzw = wrap80((int)fz - 1);
            int ox4[4], oy4[4], oz4[4];
            for (int a = 0; a < 4; ++a) {
                int xa = bxw + a; if (xa >= CX) xa -= CX;
                int ya = byw + a; if (ya >= CX) ya -= CX;
                int za = bzw + a; if (za >= CX) za -= CX;
                ox4[a] = xa * (CX*CX*3);
                oy4[a] = ya * (CX*3);
                oz4[a] = za * 3;
            }
            float a0 = 0.f, a1 = 0.f, a2 = 0.f;
            for (int a = 0; a < 4; ++a)
                for (int b = 0; b < 4; ++b)
                    for (int c = 0; c < 4; ++c) {
                        float w = wxa[a] * wya[b] * wza[c];
                        const float* pp = coeff + (ox4[a] + oy4[b] + oz4[c]);
                        a0 = fmaf(w, pp[0], a0);
                        a1 = fmaf(w, pp[1], a1);
                        a2 = fmaf(w, pp[2], a2);
                    }
            float ux = gx + a0, uy = gy + a1, uz = gz + a2;
            size_t o = (((size_t)i * FD + j) * FD + k) * 3;
            out[o + 0] = sM[16]*ux + sM[17]*uy + sM[18]*uz + sM[19];
            out[o + 1] = sM[20]*ux + sM[21]*uy + sM[22]*uz + sM[23];
            out[o + 2] = sM[24]*ux + sM[25]*uy + sM[26]*uz + sM[27];
        }
    }
}

extern "C" void kernel_launch(void* const* d_in, const int* in_sizes, int n_in,
                              void* d_out, int out_size, void* d_ws, size_t ws_size,
                              hipStream_t stream) {
    const float* coeff   = (const float*)d_in[0];
    const float* affine  = (const float*)d_in[1];
    const float* fix_aff = (const float*)d_in[2];
    const float* mov_aff = (const float*)d_in[3];
    float* out = (float*)d_out;

    // 20 * 20 * 20 tiles of 8x8x8
    spline_fused<<<8000, 256, 0, stream>>>(coeff, affine, fix_aff, mov_aff, out);
}

// Round 8
// 39.430 us; speedup vs baseline: 1.6310x; 1.6310x over previous
//
#include <hip/hip_runtime.h>

// SplineDisp: field[v] = ma @ (g(v) + cubic_bspline_pull(coeff, g(v))),
// g(v) = fa @ v, fa = inv(affine)@fix_affine, ma = inv(mov_affine)@affine.
// Fixed size: coeff [80,80,80,3] f32, out [160,160,160,3] f32.
// R8: R4 structure verbatim (3 register-window passes, no LDS, no barriers —
// every LDS-phase variant R5/R6/R7 regressed), with T1/T2 intermediates
// packed as bf16x3 in ushort4 (8 B/voxel): halves intermediate traffic and
// tap-gather cacheline counts in passes y and x.

#define CX 80
#define FD 160

__device__ inline void inv4(const float* m, float* inv) {
    inv[0]  =  m[5]*m[10]*m[15] - m[5]*m[11]*m[14] - m[9]*m[6]*m[15] + m[9]*m[7]*m[14] + m[13]*m[6]*m[11] - m[13]*m[7]*m[10];
    inv[4]  = -m[4]*m[10]*m[15] + m[4]*m[11]*m[14] + m[8]*m[6]*m[15] - m[8]*m[7]*m[14] - m[12]*m[6]*m[11] + m[12]*m[7]*m[10];
    inv[8]  =  m[4]*m[9]*m[15]  - m[4]*m[11]*m[13] - m[8]*m[5]*m[15] + m[8]*m[7]*m[13] + m[12]*m[5]*m[11] - m[12]*m[7]*m[9];
    inv[12] = -m[4]*m[9]*m[14]  + m[4]*m[10]*m[13] + m[8]*m[5]*m[14] - m[8]*m[6]*m[13] - m[12]*m[5]*m[10] + m[12]*m[6]*m[9];
    inv[1]  = -m[1]*m[10]*m[15] + m[1]*m[11]*m[14] + m[9]*m[2]*m[15] - m[9]*m[3]*m[14] - m[13]*m[2]*m[11] + m[13]*m[3]*m[10];
    inv[5]  =  m[0]*m[10]*m[15] - m[0]*m[11]*m[14] - m[8]*m[2]*m[15] + m[8]*m[3]*m[14] + m[12]*m[2]*m[11] - m[12]*m[3]*m[10];
    inv[9]  = -m[0]*m[9]*m[15]  + m[0]*m[11]*m[13] + m[8]*m[1]*m[15] - m[8]*m[3]*m[13] - m[12]*m[1]*m[11] + m[12]*m[3]*m[9];
    inv[13] =  m[0]*m[9]*m[14]  - m[0]*m[10]*m[13] - m[8]*m[1]*m[14] + m[8]*m[2]*m[13] + m[12]*m[1]*m[10] - m[12]*m[2]*m[9];
    inv[2]  =  m[1]*m[6]*m[15]  - m[1]*m[7]*m[14]  - m[5]*m[2]*m[15] + m[5]*m[3]*m[14] + m[13]*m[2]*m[7]  - m[13]*m[3]*m[6];
    inv[6]  = -m[0]*m[6]*m[15]  + m[0]*m[7]*m[14]  + m[4]*m[2]*m[15] - m[4]*m[3]*m[14] - m[12]*m[2]*m[7]  + m[12]*m[3]*m[6];
    inv[10] =  m[0]*m[5]*m[15]  - m[0]*m[7]*m[13]  - m[4]*m[1]*m[15] + m[4]*m[3]*m[13] + m[12]*m[1]*m[7]  - m[12]*m[3]*m[5];
    inv[14] = -m[0]*m[5]*m[14]  + m[0]*m[6]*m[13]  + m[4]*m[1]*m[14] - m[4]*m[2]*m[13] - m[12]*m[1]*m[6]  + m[12]*m[2]*m[5];
    inv[3]  = -m[1]*m[6]*m[11]  + m[1]*m[7]*m[10]  + m[5]*m[2]*m[11] - m[5]*m[3]*m[10] - m[9]*m[2]*m[7]   + m[9]*m[3]*m[6];
    inv[7]  =  m[0]*m[6]*m[11]  - m[0]*m[7]*m[10]  - m[4]*m[2]*m[11] + m[4]*m[3]*m[10] + m[8]*m[2]*m[7]   - m[8]*m[3]*m[6];
    inv[11] = -m[0]*m[5]*m[11]  + m[0]*m[7]*m[9]   + m[4]*m[1]*m[11] - m[4]*m[3]*m[9]  - m[8]*m[1]*m[7]   + m[8]*m[3]*m[5];
    inv[15] =  m[0]*m[5]*m[10]  - m[0]*m[6]*m[9]   - m[4]*m[1]*m[10] + m[4]*m[2]*m[9]  + m[8]*m[1]*m[6]   - m[8]*m[2]*m[5];
    float det = m[0]*inv[0] + m[1]*inv[4] + m[2]*inv[8] + m[3]*inv[12];
    float rdet = 1.0f / det;
    for (int i = 0; i < 16; ++i) inv[i] *= rdet;
}

// M[0..15]=fa, M[16..31]=ma, M[32]=separable flag (axis-aligned AND 0<diag<=1)
__global__ void setup_mats(const float* __restrict__ affine,
                           const float* __restrict__ fix_aff,
                           const float* __restrict__ mov_aff,
                           float* __restrict__ M) {
    if (threadIdx.x != 0 || blockIdx.x != 0) return;
    float invA[16], invM[16];
    inv4(affine, invA);
    inv4(mov_aff, invM);
    for (int r = 0; r < 4; ++r)
        for (int c = 0; c < 4; ++c) {
            float s = 0.f;
            for (int k = 0; k < 4; ++k) s += invA[r*4+k] * fix_aff[k*4+c];
            M[r*4+c] = s;
        }
    for (int r = 0; r < 4; ++r)
        for (int c = 0; c < 4; ++c) {
            float s = 0.f;
            for (int k = 0; k < 4; ++k) s += invM[r*4+k] * affine[k*4+c];
            M[16 + r*4+c] = s;
        }
    float od = fabsf(M[1]) + fabsf(M[2]) + fabsf(M[4]) + fabsf(M[6]) + fabsf(M[8]) + fabsf(M[9]);
    int ok = (od < 1e-20f)
          && (M[0]  > 0.f) && (M[0]  <= 1.f)
          && (M[5]  > 0.f) && (M[5]  <= 1.f)
          && (M[10] > 0.f) && (M[10] <= 1.f);
    M[32] = ok ? 1.f : 0.f;
}

__device__ inline void bspline_w(float t, float w[4]) {
    float t2 = t * t;
    float t3 = t2 * t;
    const float s = 1.0f / 6.0f;
    w[0] = (1.f - 3.f*t + 3.f*t2 - t3) * s;
    w[1] = (4.f - 6.f*t2 + 3.f*t3) * s;
    w[2] = (1.f + 3.f*t + 3.f*t2 - 3.f*t3) * s;
    w[3] = t3 * s;
}

__device__ inline int wrap80(int v) {
    int r = v % CX;
    return (r < 0) ? r + CX : r;
}

// bf16 pack (RNE) / unpack
__device__ inline unsigned short pk(float f) {
    unsigned u = __float_as_uint(f);
    u = (u + 0x7FFFu + ((u >> 16) & 1u)) >> 16;
    return (unsigned short)u;
}
__device__ inline float upk(unsigned short h) {
    return __uint_as_float((unsigned)h << 16);
}
struct F3 { float x, y, z; };
__device__ inline F3 ldT(const ushort4* p) {
    ushort4 v = *p;
    F3 r; r.x = upk(v.x); r.y = upk(v.y); r.z = upk(v.z);
    return r;
}

// Pass 1: z-interp. T1[x][y][k] = sum_c wz[k][c]*coeff[x][y][zc]. 1,024,000 thr.
__global__ __launch_bounds__(256) void pass_z(const float* __restrict__ coeff,
                                              const float* __restrict__ M,
                                              ushort4* __restrict__ T1) {
    if (M[32] == 0.f) return;
    int tid = blockIdx.x * 256 + threadIdx.x;
    int k = tid % FD;
    int r = tid / FD;          // r = x*80 + y
    float gz = M[10] * (float)k + M[11];
    float fz = floorf(gz);
    float wz[4];
    bspline_w(gz - fz, wz);
    int bz = wrap80((int)fz - 1);
    const float* base = coeff + (size_t)r * (CX * 3);
    float a0 = 0.f, a1 = 0.f, a2 = 0.f;
#pragma unroll
    for (int c = 0; c < 4; ++c) {
        int zc = bz + c; if (zc >= CX) zc -= CX;
        const float* p = base + zc * 3;
        float w = wz[c];
        a0 = fmaf(w, p[0], a0);
        a1 = fmaf(w, p[1], a1);
        a2 = fmaf(w, p[2], a2);
    }
    ushort4 v; v.x = pk(a0); v.y = pk(a1); v.z = pk(a2); v.w = 0;
    T1[tid] = v;
}

// Pass 2: y-interp, coarsened 8 j's per thread with register sliding window.
// T2[x][j][k] = sum_b wy[j][b] * T1[x][yb][k]. 80*20*160 = 256,000 threads.
__global__ __launch_bounds__(256) void pass_y_c(const float* __restrict__ M,
                                                const ushort4* __restrict__ T1,
                                                ushort4* __restrict__ T2) {
    if (M[32] == 0.f) return;
    int tid = blockIdx.x * 256 + threadIdx.x;
    int k = tid % FD;
    int r = tid / FD;
    int jg = r % 20;
    int x = r / 20;
    int j0 = jg * 8;

    const float m5 = M[5], m7 = M[7];
    const ushort4* Tx = T1 + (size_t)x * CX * FD + k;

    float gy = m5 * (float)j0 + m7;
    float fy = floorf(gy);
    int nb = (int)fy - 1;
    float wy[4];
    bspline_w(gy - fy, wy);

    F3 w0, w1, w2, w3;
    {
        int y0 = wrap80(nb);
        int y1 = y0 + 1; if (y1 >= CX) y1 -= CX;
        int y2 = y1 + 1; if (y2 >= CX) y2 -= CX;
        int y3 = y2 + 1; if (y3 >= CX) y3 -= CX;
        w0 = ldT(Tx + (size_t)y0 * FD);
        w1 = ldT(Tx + (size_t)y1 * FD);
        w2 = ldT(Tx + (size_t)y2 * FD);
        w3 = ldT(Tx + (size_t)y3 * FD);
    }

    ushort4* To = T2 + ((size_t)(x * FD + j0)) * FD + k;
#pragma unroll
    for (int d = 0; d < 8; ++d) {
        if (d > 0) {
            int j = j0 + d;
            gy = m5 * (float)j + m7;
            fy = floorf(gy);
            int b2 = (int)fy - 1;
            if (b2 != nb) {                 // advance window by 1 (stride<=1)
                w0 = w1; w1 = w2; w2 = w3;
                w3 = ldT(Tx + (size_t)wrap80(b2 + 3) * FD);
                nb = b2;
            }
            bspline_w(gy - fy, wy);
        }
        float a0 = wy[0]*w0.x + wy[1]*w1.x + wy[2]*w2.x + wy[3]*w3.x;
        float a1 = wy[0]*w0.y + wy[1]*w1.y + wy[2]*w2.y + wy[3]*w3.y;
        float a2 = wy[0]*w0.z + wy[1]*w1.z + wy[2]*w2.z + wy[3]*w3.z;
        ushort4 v; v.x = pk(a0); v.y = pk(a1); v.z = pk(a2); v.w = 0;
        To[(size_t)d * FD] = v;
    }
}

// Pass 3: x-interp + displacement + ma affine, coarsened 8 i's per thread.
// 20*160*160 = 512,000 threads.
__global__ __launch_bounds__(256) void pass_x_c(const float* __restrict__ coeff,
                                                const float* __restrict__ M,
                                                const ushort4* __restrict__ T2,
                                                float* __restrict__ out) {
    int tid = blockIdx.x * 256 + threadIdx.x;
    int k = tid % FD;
    int r = tid / FD;
    int j = r % FD;
    int ig = r / FD;
    int i0 = ig * 8;

    if (M[32] != 0.f) {
        const float m0 = M[0], m3 = M[3];
        const float gy = M[5] * (float)j + M[7];
        const float gz = M[10] * (float)k + M[11];
        const ushort4* Tjk = T2 + (size_t)j * FD + k;

        float gx = m0 * (float)i0 + m3;
        float fx = floorf(gx);
        int nb = (int)fx - 1;
        float wx[4];
        bspline_w(gx - fx, wx);

        F3 w0, w1, w2, w3;
        {
            int x0 = wrap80(nb);
            int x1 = x0 + 1; if (x1 >= CX) x1 -= CX;
            int x2 = x1 + 1; if (x2 >= CX) x2 -= CX;
            int x3 = x2 + 1; if (x3 >= CX) x3 -= CX;
            w0 = ldT(Tjk + (size_t)x0 * FD * FD);
            w1 = ldT(Tjk + (size_t)x1 * FD * FD);
            w2 = ldT(Tjk + (size_t)x2 * FD * FD);
            w3 = ldT(Tjk + (size_t)x3 * FD * FD);
        }

        float* po = out + (((size_t)(i0 * FD + j)) * FD + k) * 3;
#pragma unroll
        for (int d = 0; d < 8; ++d) {
            float gxd = gx;
            if (d > 0) {
                int i = i0 + d;
                gxd = m0 * (float)i + m3;
                float fx2 = floorf(gxd);
                int b2 = (int)fx2 - 1;
                if (b2 != nb) {
                    w0 = w1; w1 = w2; w2 = w3;
                    w3 = ldT(Tjk + (size_t)wrap80(b2 + 3) * FD * FD);
                    nb = b2;
                }
                bspline_w(gxd - fx2, wx);
            }
            float a0 = wx[0]*w0.x + wx[1]*w1.x + wx[2]*w2.x + wx[3]*w3.x;
            float a1 = wx[0]*w0.y + wx[1]*w1.y + wx[2]*w2.y + wx[3]*w3.y;
            float a2 = wx[0]*w0.z + wx[1]*w1.z + wx[2]*w2.z + wx[3]*w3.z;
            float ux = gxd + a0, uy = gy + a1, uz = gz + a2;
            po[0] = M[16]*ux + M[17]*uy + M[18]*uz + M[19];
            po[1] = M[20]*ux + M[21]*uy + M[22]*uz + M[23];
            po[2] = M[24]*ux + M[25]*uy + M[26]*uz + M[27];
            po += (size_t)FD * FD * 3;   // advance i by 1
        }
    } else {
        // non-separable fallback: direct 64-tap per output
        for (int d = 0; d < 8; ++d) {
            int i = i0 + d;
            float fi = (float)i, fj = (float)j, fk = (float)k;
            float gx = M[0]*fi + M[1]*fj + M[2]*fk  + M[3];
            float gy = M[4]*fi + M[5]*fj + M[6]*fk  + M[7];
            float gz = M[8]*fi + M[9]*fj + M[10]*fk + M[11];
            float fx = floorf(gx), fy = floorf(gy), fz = floorf(gz);
            float wx[4], wy[4], wz[4];
            bspline_w(gx - fx, wx);
            bspline_w(gy - fy, wy);
            bspline_w(gz - fz, wz);
            int bxw = wrap80((int)fx - 1);
            int byw = wrap80((int)fy - 1);
            int bzw = wrap80((int)fz - 1);
            int ox[4], oy[4], oz[4];
            for (int a = 0; a < 4; ++a) {
                int xa = bxw + a; if (xa >= CX) xa -= CX;
                int ya = byw + a; if (ya >= CX) ya -= CX;
                int za = bzw + a; if (za >= CX) za -= CX;
                ox[a] = xa * (CX*CX*3);
                oy[a] = ya * (CX*3);
                oz[a] = za * 3;
            }
            float a0 = 0.f, a1 = 0.f, a2 = 0.f;
            for (int a = 0; a < 4; ++a)
                for (int b = 0; b < 4; ++b)
                    for (int c = 0; c < 4; ++c) {
                        float w = wx[a] * wy[b] * wz[c];
                        const float* p = coeff + (ox[a] + oy[b] + oz[c]);
                        a0 = fmaf(w, p[0], a0);
                        a1 = fmaf(w, p[1], a1);
                        a2 = fmaf(w, p[2], a2);
                    }
            float ux = gx + a0, uy = gy + a1, uz = gz + a2;
            size_t o = ((size_t)(i * FD + j) * FD + k) * 3;
            out[o + 0] = M[16]*ux + M[17]*uy + M[18]*uz + M[19];
            out[o + 1] = M[20]*ux + M[21]*uy + M[22]*uz + M[23];
            out[o + 2] = M[24]*ux + M[25]*uy + M[26]*uz + M[27];
        }
    }
}

// Direct path used when ws can't hold intermediates.
__global__ __launch_bounds__(256) void spline_direct(const float* __restrict__ coeff,
                                                     const float* __restrict__ M,
                                                     float* __restrict__ out) {
    int tid = blockIdx.x * 256 + threadIdx.x;
    int k = tid % FD;
    int r = tid / FD;
    int j = r % FD;
    int i = r / FD;
    float fi = (float)i, fj = (float)j, fk = (float)k;
    float gx = M[0]*fi + M[1]*fj + M[2]*fk  + M[3];
    float gy = M[4]*fi + M[5]*fj + M[6]*fk  + M[7];
    float gz = M[8]*fi + M[9]*fj + M[10]*fk + M[11];
    float fx = floorf(gx), fy = floorf(gy), fz = floorf(gz);
    float wx[4], wy[4], wz[4];
    bspline_w(gx - fx, wx);
    bspline_w(gy - fy, wy);
    bspline_w(gz - fz, wz);
    int bxw = wrap80((int)fx - 1);
    int byw = wrap80((int)fy - 1);
    int bzw = wrap80((int)fz - 1);
    int ox[4], oy[4], oz[4];
#pragma unroll
    for (int a = 0; a < 4; ++a) {
        int xa = bxw + a; if (xa >= CX) xa -= CX;
        int ya = byw + a; if (ya >= CX) ya -= CX;
        int za = bzw + a; if (za >= CX) za -= CX;
        ox[a] = xa * (CX*CX*3);
        oy[a] = ya * (CX*3);
        oz[a] = za * 3;
    }
    float a0 = 0.f, a1 = 0.f, a2 = 0.f;
#pragma unroll
    for (int a = 0; a < 4; ++a)
#pragma unroll
        for (int b = 0; b < 4; ++b)
#pragma unroll
            for (int c = 0; c < 4; ++c) {
                float w = wx[a] * wy[b] * wz[c];
                const float* p = coeff + (ox[a] + oy[b] + oz[c]);
                a0 = fmaf(w, p[0], a0);
                a1 = fmaf(w, p[1], a1);
                a2 = fmaf(w, p[2], a2);
            }
    float ux = gx + a0, uy = gy + a1, uz = gz + a2;
    out[tid*3 + 0] = M[16]*ux + M[17]*uy + M[18]*uz + M[19];
    out[tid*3 + 1] = M[20]*ux + M[21]*uy + M[22]*uz + M[23];
    out[tid*3 + 2] = M[24]*ux + M[25]*uy + M[26]*uz + M[27];
}

extern "C" void kernel_launch(void* const* d_in, const int* in_sizes, int n_in,
                              void* d_out, int out_size, void* d_ws, size_t ws_size,
                              hipStream_t stream) {
    const float* coeff   = (const float*)d_in[0];
    const float* affine  = (const float*)d_in[1];
    const float* fix_aff = (const float*)d_in[2];
    const float* mov_aff = (const float*)d_in[3];
    float* M    = (float*)d_ws;                                   // 64 floats
    char*  ws   = (char*)d_ws;
    ushort4* T1 = (ushort4*)(ws + 256);                           // 8,192,000 B
    ushort4* T2 = (ushort4*)(ws + 256 + (size_t)CX*CX*FD*8);      // 16,384,000 B
    float* out  = (float*)d_out;

    const size_t need = 256 + (size_t)CX*CX*FD*8 + (size_t)CX*FD*FD*8;

    setup_mats<<<1, 64, 0, stream>>>(affine, fix_aff, mov_aff, M);

    if (ws_size >= need) {
        pass_z<<<(CX*CX*FD)/256, 256, 0, stream>>>(coeff, M, T1);
        pass_y_c<<<(CX*20*FD)/256, 256, 0, stream>>>(M, T1, T2);
        pass_x_c<<<(20*FD*FD)/256, 256, 0, stream>>>(coeff, M, T2, out);
    } else {
        spline_direct<<<(FD*FD*FD)/256, 256, 0, stream>>>(coeff, M, out);
    }
}

// Round 9
// 39.293 us; speedup vs baseline: 1.6368x; 1.0035x over previous
//
#include <hip/hip_runtime.h>

// SplineDisp: field[v] = ma @ (g(v) + cubic_bspline_pull(coeff, g(v))),
// g(v) = fa @ v, fa = inv(affine)@fix_affine, ma = inv(mov_affine)@affine.
// Fixed size: coeff [80,80,80,3] f32, out [160,160,160,3] f32.
// R9: R8 (3 register-window passes, bf16x3 intermediates) + preloaded
// 12-row shift-queue in passes y and x: all window rows loaded up-front
// (independent, 12-deep MLP), window advance is a register shift — removes
// the serial advance-load latency chain that R8 exposed.

#define CX 80
#define FD 160

__device__ inline void inv4(const float* m, float* inv) {
    inv[0]  =  m[5]*m[10]*m[15] - m[5]*m[11]*m[14] - m[9]*m[6]*m[15] + m[9]*m[7]*m[14] + m[13]*m[6]*m[11] - m[13]*m[7]*m[10];
    inv[4]  = -m[4]*m[10]*m[15] + m[4]*m[11]*m[14] + m[8]*m[6]*m[15] - m[8]*m[7]*m[14] - m[12]*m[6]*m[11] + m[12]*m[7]*m[10];
    inv[8]  =  m[4]*m[9]*m[15]  - m[4]*m[11]*m[13] - m[8]*m[5]*m[15] + m[8]*m[7]*m[13] + m[12]*m[5]*m[11] - m[12]*m[7]*m[9];
    inv[12] = -m[4]*m[9]*m[14]  + m[4]*m[10]*m[13] + m[8]*m[5]*m[14] - m[8]*m[6]*m[13] - m[12]*m[5]*m[10] + m[12]*m[6]*m[9];
    inv[1]  = -m[1]*m[10]*m[15] + m[1]*m[11]*m[14] + m[9]*m[2]*m[15] - m[9]*m[3]*m[14] - m[13]*m[2]*m[11] + m[13]*m[3]*m[10];
    inv[5]  =  m[0]*m[10]*m[15] - m[0]*m[11]*m[14] - m[8]*m[2]*m[15] + m[8]*m[3]*m[14] + m[12]*m[2]*m[11] - m[12]*m[3]*m[10];
    inv[9]  = -m[0]*m[9]*m[15]  + m[0]*m[11]*m[13] + m[8]*m[1]*m[15] - m[8]*m[3]*m[13] - m[12]*m[1]*m[11] + m[12]*m[3]*m[9];
    inv[13] =  m[0]*m[9]*m[14]  - m[0]*m[10]*m[13] - m[8]*m[1]*m[14] + m[8]*m[2]*m[13] + m[12]*m[1]*m[10] - m[12]*m[2]*m[9];
    inv[2]  =  m[1]*m[6]*m[15]  - m[1]*m[7]*m[14]  - m[5]*m[2]*m[15] + m[5]*m[3]*m[14] + m[13]*m[2]*m[7]  - m[13]*m[3]*m[6];
    inv[6]  = -m[0]*m[6]*m[15]  + m[0]*m[7]*m[14]  + m[4]*m[2]*m[15] - m[4]*m[3]*m[14] - m[12]*m[2]*m[7]  + m[12]*m[3]*m[6];
    inv[10] =  m[0]*m[5]*m[15]  - m[0]*m[7]*m[13]  - m[4]*m[1]*m[15] + m[4]*m[3]*m[13] + m[12]*m[1]*m[7]  - m[12]*m[3]*m[5];
    inv[14] = -m[0]*m[5]*m[14]  + m[0]*m[6]*m[13]  + m[4]*m[1]*m[14] - m[4]*m[2]*m[13] - m[12]*m[1]*m[6]  + m[12]*m[2]*m[5];
    inv[3]  = -m[1]*m[6]*m[11]  + m[1]*m[7]*m[10]  + m[5]*m[2]*m[11] - m[5]*m[3]*m[10] - m[9]*m[2]*m[7]   + m[9]*m[3]*m[6];
    inv[7]  =  m[0]*m[6]*m[11]  - m[0]*m[7]*m[10]  - m[4]*m[2]*m[11] + m[4]*m[3]*m[10] + m[8]*m[2]*m[7]   - m[8]*m[3]*m[6];
    inv[11] = -m[0]*m[5]*m[11]  + m[0]*m[7]*m[9]   + m[4]*m[1]*m[11] - m[4]*m[3]*m[9]  - m[8]*m[1]*m[7]   + m[8]*m[3]*m[5];
    inv[15] =  m[0]*m[5]*m[10]  - m[0]*m[6]*m[9]   - m[4]*m[1]*m[10] + m[4]*m[2]*m[9]  + m[8]*m[1]*m[6]   - m[8]*m[2]*m[5];
    float det = m[0]*inv[0] + m[1]*inv[4] + m[2]*inv[8] + m[3]*inv[12];
    float rdet = 1.0f / det;
    for (int i = 0; i < 16; ++i) inv[i] *= rdet;
}

// M[0..15]=fa, M[16..31]=ma, M[32]=separable flag (axis-aligned AND 0<diag<=1)
__global__ void setup_mats(const float* __restrict__ affine,
                           const float* __restrict__ fix_aff,
                           const float* __restrict__ mov_aff,
                           float* __restrict__ M) {
    if (threadIdx.x != 0 || blockIdx.x != 0) return;
    float invA[16], invM[16];
    inv4(affine, invA);
    inv4(mov_aff, invM);
    for (int r = 0; r < 4; ++r)
        for (int c = 0; c < 4; ++c) {
            float s = 0.f;
            for (int k = 0; k < 4; ++k) s += invA[r*4+k] * fix_aff[k*4+c];
            M[r*4+c] = s;
        }
    for (int r = 0; r < 4; ++r)
        for (int c = 0; c < 4; ++c) {
            float s = 0.f;
            for (int k = 0; k < 4; ++k) s += invM[r*4+k] * affine[k*4+c];
            M[16 + r*4+c] = s;
        }
    float od = fabsf(M[1]) + fabsf(M[2]) + fabsf(M[4]) + fabsf(M[6]) + fabsf(M[8]) + fabsf(M[9]);
    int ok = (od < 1e-20f)
          && (M[0]  > 0.f) && (M[0]  <= 1.f)
          && (M[5]  > 0.f) && (M[5]  <= 1.f)
          && (M[10] > 0.f) && (M[10] <= 1.f);
    M[32] = ok ? 1.f : 0.f;
}

__device__ inline void bspline_w(float t, float w[4]) {
    float t2 = t * t;
    float t3 = t2 * t;
    const float s = 1.0f / 6.0f;
    w[0] = (1.f - 3.f*t + 3.f*t2 - t3) * s;
    w[1] = (4.f - 6.f*t2 + 3.f*t3) * s;
    w[2] = (1.f + 3.f*t + 3.f*t2 - 3.f*t3) * s;
    w[3] = t3 * s;
}

__device__ inline int wrap80(int v) {
    int r = v % CX;
    return (r < 0) ? r + CX : r;
}

// bf16 pack (RNE) / unpack
__device__ inline unsigned short pk(float f) {
    unsigned u = __float_as_uint(f);
    u = (u + 0x7FFFu + ((u >> 16) & 1u)) >> 16;
    return (unsigned short)u;
}
__device__ inline float upk(unsigned short h) {
    return __uint_as_float((unsigned)h << 16);
}

// Pass 1: z-interp. T1[x][y][k] = sum_c wz[k][c]*coeff[x][y][zc]. 1,024,000 thr.
__global__ __launch_bounds__(256) void pass_z(const float* __restrict__ coeff,
                                              const float* __restrict__ M,
                                              ushort4* __restrict__ T1) {
    if (M[32] == 0.f) return;
    int tid = blockIdx.x * 256 + threadIdx.x;
    int k = tid % FD;
    int r = tid / FD;          // r = x*80 + y
    float gz = M[10] * (float)k + M[11];
    float fz = floorf(gz);
    float wz[4];
    bspline_w(gz - fz, wz);
    int bz = wrap80((int)fz - 1);
    const float* base = coeff + (size_t)r * (CX * 3);
    float a0 = 0.f, a1 = 0.f, a2 = 0.f;
#pragma unroll
    for (int c = 0; c < 4; ++c) {
        int zc = bz + c; if (zc >= CX) zc -= CX;
        const float* p = base + zc * 3;
        float w = wz[c];
        a0 = fmaf(w, p[0], a0);
        a1 = fmaf(w, p[1], a1);
        a2 = fmaf(w, p[2], a2);
    }
    ushort4 v; v.x = pk(a0); v.y = pk(a1); v.z = pk(a2); v.w = 0;
    T1[tid] = v;
}

// Pass 2: y-interp, coarsened 8 j's/thread. Preloaded 12-row shift-queue.
// T2[x][j][k] = sum_b wy[j][b] * T1[x][yb][k]. 80*20*160 = 256,000 threads.
__global__ __launch_bounds__(256) void pass_y_c(const float* __restrict__ M,
                                                const ushort4* __restrict__ T1,
                                                ushort4* __restrict__ T2) {
    if (M[32] == 0.f) return;
    int tid = blockIdx.x * 256 + threadIdx.x;
    int k = tid % FD;
    int r = tid / FD;
    int jg = r % 20;
    int x = r / 20;
    int j0 = jg * 8;

    const float m5 = M[5], m7 = M[7];
    const ushort4* Tx = T1 + (size_t)x * CX * FD + k;

    float gy = m5 * (float)j0 + m7;
    float fy = floorf(gy);
    int nb = (int)fy - 1;
    float wy[4];
    bspline_w(gy - fy, wy);

    // preload rows nb..nb+11 (wrapped): all independent loads, one wait
    ushort4 w0, w1, w2, w3, q4, q5, q6, q7, q8, q9, q10, q11;
    {
        int rw = wrap80(nb);
        int r1 = rw+1;  if (r1  >= CX) r1  -= CX;
        int r2 = r1+1;  if (r2  >= CX) r2  -= CX;
        int r3 = r2+1;  if (r3  >= CX) r3  -= CX;
        int r4 = r3+1;  if (r4  >= CX) r4  -= CX;
        int r5 = r4+1;  if (r5  >= CX) r5  -= CX;
        int r6 = r5+1;  if (r6  >= CX) r6  -= CX;
        int r7 = r6+1;  if (r7  >= CX) r7  -= CX;
        int r8 = r7+1;  if (r8  >= CX) r8  -= CX;
        int r9 = r8+1;  if (r9  >= CX) r9  -= CX;
        int rA = r9+1;  if (rA  >= CX) rA  -= CX;
        int rB = rA+1;  if (rB  >= CX) rB  -= CX;
        w0  = Tx[(size_t)rw * FD];
        w1  = Tx[(size_t)r1 * FD];
        w2  = Tx[(size_t)r2 * FD];
        w3  = Tx[(size_t)r3 * FD];
        q4  = Tx[(size_t)r4 * FD];
        q5  = Tx[(size_t)r5 * FD];
        q6  = Tx[(size_t)r6 * FD];
        q7  = Tx[(size_t)r7 * FD];
        q8  = Tx[(size_t)r8 * FD];
        q9  = Tx[(size_t)r9 * FD];
        q10 = Tx[(size_t)rA * FD];
        q11 = Tx[(size_t)rB * FD];
    }

    ushort4* To = T2 + ((size_t)(x * FD + j0)) * FD + k;
#pragma unroll
    for (int d = 0; d < 8; ++d) {
        if (d > 0) {
            int j = j0 + d;
            gy = m5 * (float)j + m7;
            fy = floorf(gy);
            int b2 = (int)fy - 1;
            if (b2 != nb) {                 // advance window: pure register shift
                w0 = w1; w1 = w2; w2 = w3; w3 = q4;
                q4 = q5; q5 = q6; q6 = q7; q7 = q8;
                q8 = q9; q9 = q10; q10 = q11;
                nb = b2;
            }
            bspline_w(gy - fy, wy);
        }
        float a0 = wy[0]*upk(w0.x) + wy[1]*upk(w1.x) + wy[2]*upk(w2.x) + wy[3]*upk(w3.x);
        float a1 = wy[0]*upk(w0.y) + wy[1]*upk(w1.y) + wy[2]*upk(w2.y) + wy[3]*upk(w3.y);
        float a2 = wy[0]*upk(w0.z) + wy[1]*upk(w1.z) + wy[2]*upk(w2.z) + wy[3]*upk(w3.z);
        ushort4 v; v.x = pk(a0); v.y = pk(a1); v.z = pk(a2); v.w = 0;
        To[(size_t)d * FD] = v;
    }
}

// Pass 3: x-interp + displacement + ma affine, coarsened 8 i's/thread.
// Preloaded 12-row shift-queue. 20*160*160 = 512,000 threads.
__global__ __launch_bounds__(256) void pass_x_c(const float* __restrict__ coeff,
                                                const float* __restrict__ M,
                                                const ushort4* __restrict__ T2,
                                                float* __restrict__ out) {
    int tid = blockIdx.x * 256 + threadIdx.x;
    int k = tid % FD;
    int r = tid / FD;
    int j = r % FD;
    int ig = r / FD;
    int i0 = ig * 8;

    if (M[32] != 0.f) {
        const float m0 = M[0], m3 = M[3];
        const float gy = M[5] * (float)j + M[7];
        const float gz = M[10] * (float)k + M[11];
        const ushort4* Tjk = T2 + (size_t)j * FD + k;

        float gx = m0 * (float)i0 + m3;
        float fx = floorf(gx);
        int nb = (int)fx - 1;
        float wx[4];
        bspline_w(gx - fx, wx);

        ushort4 w0, w1, w2, w3, q4, q5, q6, q7, q8, q9, q10, q11;
        {
            const size_t S = (size_t)FD * FD;
            int rw = wrap80(nb);
            int r1 = rw+1;  if (r1  >= CX) r1  -= CX;
            int r2 = r1+1;  if (r2  >= CX) r2  -= CX;
            int r3 = r2+1;  if (r3  >= CX) r3  -= CX;
            int r4 = r3+1;  if (r4  >= CX) r4  -= CX;
            int r5 = r4+1;  if (r5  >= CX) r5  -= CX;
            int r6 = r5+1;  if (r6  >= CX) r6  -= CX;
            int r7 = r6+1;  if (r7  >= CX) r7  -= CX;
            int r8 = r7+1;  if (r8  >= CX) r8  -= CX;
            int r9 = r8+1;  if (r9  >= CX) r9  -= CX;
            int rA = r9+1;  if (rA  >= CX) rA  -= CX;
            int rB = rA+1;  if (rB  >= CX) rB  -= CX;
            w0  = Tjk[(size_t)rw * S];
            w1  = Tjk[(size_t)r1 * S];
            w2  = Tjk[(size_t)r2 * S];
            w3  = Tjk[(size_t)r3 * S];
            q4  = Tjk[(size_t)r4 * S];
            q5  = Tjk[(size_t)r5 * S];
            q6  = Tjk[(size_t)r6 * S];
            q7  = Tjk[(size_t)r7 * S];
            q8  = Tjk[(size_t)r8 * S];
            q9  = Tjk[(size_t)r9 * S];
            q10 = Tjk[(size_t)rA * S];
            q11 = Tjk[(size_t)rB * S];
        }

        float* po = out + (((size_t)(i0 * FD + j)) * FD + k) * 3;
#pragma unroll
        for (int d = 0; d < 8; ++d) {
            float gxd = gx;
            if (d > 0) {
                int i = i0 + d;
                gxd = m0 * (float)i + m3;
                float fx2 = floorf(gxd);
                int b2 = (int)fx2 - 1;
                if (b2 != nb) {             // advance window: pure register shift
                    w0 = w1; w1 = w2; w2 = w3; w3 = q4;
                    q4 = q5; q5 = q6; q6 = q7; q7 = q8;
                    q8 = q9; q9 = q10; q10 = q11;
                    nb = b2;
                }
                bspline_w(gxd - fx2, wx);
            }
            float a0 = wx[0]*upk(w0.x) + wx[1]*upk(w1.x) + wx[2]*upk(w2.x) + wx[3]*upk(w3.x);
            float a1 = wx[0]*upk(w0.y) + wx[1]*upk(w1.y) + wx[2]*upk(w2.y) + wx[3]*upk(w3.y);
            float a2 = wx[0]*upk(w0.z) + wx[1]*upk(w1.z) + wx[2]*upk(w2.z) + wx[3]*upk(w3.z);
            float ux = gxd + a0, uy = gy + a1, uz = gz + a2;
            po[0] = M[16]*ux + M[17]*uy + M[18]*uz + M[19];
            po[1] = M[20]*ux + M[21]*uy + M[22]*uz + M[23];
            po[2] = M[24]*ux + M[25]*uy + M[26]*uz + M[27];
            po += (size_t)FD * FD * 3;   // advance i by 1
        }
    } else {
        // non-separable fallback: direct 64-tap per output
        for (int d = 0; d < 8; ++d) {
            int i = i0 + d;
            float fi = (float)i, fj = (float)j, fk = (float)k;
            float gx = M[0]*fi + M[1]*fj + M[2]*fk  + M[3];
            float gy = M[4]*fi + M[5]*fj + M[6]*fk  + M[7];
            float gz = M[8]*fi + M[9]*fj + M[10]*fk + M[11];
            float fx = floorf(gx), fy = floorf(gy), fz = floorf(gz);
            float wx[4], wy[4], wz[4];
            bspline_w(gx - fx, wx);
            bspline_w(gy - fy, wy);
            bspline_w(gz - fz, wz);
            int bxw = wrap80((int)fx - 1);
            int byw = wrap80((int)fy - 1);
            int bzw = wrap80((int)fz - 1);
            int ox[4], oy[4], oz[4];
            for (int a = 0; a < 4; ++a) {
                int xa = bxw + a; if (xa >= CX) xa -= CX;
                int ya = byw + a; if (ya >= CX) ya -= CX;
                int za = bzw + a; if (za >= CX) za -= CX;
                ox[a] = xa * (CX*CX*3);
                oy[a] = ya * (CX*3);
                oz[a] = za * 3;
            }
            float a0 = 0.f, a1 = 0.f, a2 = 0.f;
            for (int a = 0; a < 4; ++a)
                for (int b = 0; b < 4; ++b)
                    for (int c = 0; c < 4; ++c) {
                        float w = wx[a] * wy[b] * wz[c];
                        const float* p = coeff + (ox[a] + oy[b] + oz[c]);
                        a0 = fmaf(w, p[0], a0);
                        a1 = fmaf(w, p[1], a1);
                        a2 = fmaf(w, p[2], a2);
                    }
            float ux = gx + a0, uy = gy + a1, uz = gz + a2;
            size_t o = ((size_t)(i * FD + j) * FD + k) * 3;
            out[o + 0] = M[16]*ux + M[17]*uy + M[18]*uz + M[19];
            out[o + 1] = M[20]*ux + M[21]*uy + M[22]*uz + M[23];
            out[o + 2] = M[24]*ux + M[25]*uy + M[26]*uz + M[27];
        }
    }
}

// Direct path used when ws can't hold intermediates.
__global__ __launch_bounds__(256) void spline_direct(const float* __restrict__ coeff,
                                                     const float* __restrict__ M,
                                                     float* __restrict__ out) {
    int tid = blockIdx.x * 256 + threadIdx.x;
    int k = tid % FD;
    int r = tid / FD;
    int j = r % FD;
    int i = r / FD;
    float fi = (float)i, fj = (float)j, fk = (float)k;
    float gx = M[0]*fi + M[1]*fj + M[2]*fk  + M[3];
    float gy = M[4]*fi + M[5]*fj + M[6]*fk  + M[7];
    float gz = M[8]*fi + M[9]*fj + M[10]*fk + M[11];
    float fx = floorf(gx), fy = floorf(gy), fz = floorf(gz);
    float wx[4], wy[4], wz[4];
    bspline_w(gx - fx, wx);
    bspline_w(gy - fy, wy);
    bspline_w(gz - fz, wz);
    int bxw = wrap80((int)fx - 1);
    int byw = wrap80((int)fy - 1);
    int bzw = wrap80((int)fz - 1);
    int ox[4], oy[4], oz[4];
#pragma unroll
    for (int a = 0; a < 4; ++a) {
        int xa = bxw + a; if (xa >= CX) xa -= CX;
        int ya = byw + a; if (ya >= CX) ya -= CX;
        int za = bzw + a; if (za >= CX) za -= CX;
        ox[a] = xa * (CX*CX*3);
        oy[a] = ya * (CX*3);
        oz[a] = za * 3;
    }
    float a0 = 0.f, a1 = 0.f, a2 = 0.f;
#pragma unroll
    for (int a = 0; a < 4; ++a)
#pragma unroll
        for (int b = 0; b < 4; ++b)
#pragma unroll
            for (int c = 0; c < 4; ++c) {
                float w = wx[a] * wy[b] * wz[c];
                const float* p = coeff + (ox[a] + oy[b] + oz[c]);
                a0 = fmaf(w, p[0], a0);
                a1 = fmaf(w, p[1], a1);
                a2 = fmaf(w, p[2], a2);
            }
    float ux = gx + a0, uy = gy + a1, uz = gz + a2;
    out[tid*3 + 0] = M[16]*ux + M[17]*uy + M[18]*uz + M[19];
    out[tid*3 + 1] = M[20]*ux + M[21]*uy + M[22]*uz + M[23];
    out[tid*3 + 2] = M[24]*ux + M[25]*uy + M[26]*uz + M[27];
}

extern "C" void kernel_launch(void* const* d_in, const int* in_sizes, int n_in,
                              void* d_out, int out_size, void* d_ws, size_t ws_size,
                              hipStream_t stream) {
    const float* coeff   = (const float*)d_in[0];
    const float* affine  = (const float*)d_in[1];
    const float* fix_aff = (const float*)d_in[2];
    const float* mov_aff = (const float*)d_in[3];
    float* M    = (float*)d_ws;                                   // 64 floats
    char*  ws   = (char*)d_ws;
    ushort4* T1 = (ushort4*)(ws + 256);                           // 8,192,000 B
    ushort4* T2 = (ushort4*)(ws + 256 + (size_t)CX*CX*FD*8);      // 16,384,000 B
    float* out  = (float*)d_out;

    const size_t need = 256 + (size_t)CX*CX*FD*8 + (size_t)CX*FD*FD*8;

    setup_mats<<<1, 64, 0, stream>>>(affine, fix_aff, mov_aff, M);

    if (ws_size >= need) {
        pass_z<<<(CX*CX*FD)/256, 256, 0, stream>>>(coeff, M, T1);
        pass_y_c<<<(CX*20*FD)/256, 256, 0, stream>>>(M, T1, T2);
        pass_x_c<<<(20*FD*FD)/256, 256, 0, stream>>>(coeff, M, T2, out);
    } else {
        spline_direct<<<(FD*FD*FD)/256, 256, 0, stream>>>(coeff, M, out);
    }
}